// Round 3
// baseline (10521.690 us; speedup 1.0000x reference)
//
#include <hip/hip_runtime.h>
#include <cstdint>
#include <cstddef>

#define ROW  36997ULL   // 64 + 32768 + 1 + 1 + 1 + 64 + 4096 + 1 + 1
#define NBLK 256

using frag_ab = __attribute__((ext_vector_type(8))) short;  // 8 bf16 (4 VGPRs)
using frag_cd = __attribute__((ext_vector_type(4))) float;  // 4 fp32

__device__ __forceinline__ float dot4(float4 a, float4 b) {
    return a.x * b.x + a.y * b.y + a.z * b.z + a.w * b.w;
}
__device__ __forceinline__ float sigmoidf_(float x) { return 1.f / (1.f + expf(-x)); }
__device__ __forceinline__ float softplusf_(float x) { return fmaxf(x, 0.f) + log1pf(expf(-fabsf(x))); }
// RNE f32 -> bf16 (finite values only)
__device__ __forceinline__ ushort f2b(float x) {
    uint32_t u = __float_as_uint(x);
    u += 0x7FFFu + ((u >> 16) & 1u);
    return (ushort)(u >> 16);
}

// ---------------------------------------------------------------------------
// Tree grid-barrier: 8 leaf counters (padded) -> root -> generation flag.
// AGENT-scope acq/rel gives cross-XCD visibility (each block's acquire
// invalidates its own L1/XCD-L2; each release writes back dirty lines).
// ---------------------------------------------------------------------------
__device__ __forceinline__ void gbar(int* __restrict__ bar) {
    __syncthreads();
    if (threadIdx.x == 0) {
        int* leaf = bar + (blockIdx.x & 7) * 32;
        int* root = bar + 256;
        int* gen  = bar + 288;
        int g = __hip_atomic_load(gen, __ATOMIC_RELAXED, __HIP_MEMORY_SCOPE_AGENT);
        bool last = false;
        int lc = __hip_atomic_fetch_add(leaf, 1, __ATOMIC_ACQ_REL, __HIP_MEMORY_SCOPE_AGENT);
        if (lc == NBLK / 8 - 1) {
            __hip_atomic_store(leaf, 0, __ATOMIC_RELAXED, __HIP_MEMORY_SCOPE_AGENT);
            int rc = __hip_atomic_fetch_add(root, 1, __ATOMIC_ACQ_REL, __HIP_MEMORY_SCOPE_AGENT);
            if (rc == 7) {
                __hip_atomic_store(root, 0, __ATOMIC_RELAXED, __HIP_MEMORY_SCOPE_AGENT);
                __hip_atomic_store(gen, g + 1, __ATOMIC_RELEASE, __HIP_MEMORY_SCOPE_AGENT);
                last = true;
            }
        }
        if (!last)
            while (__hip_atomic_load(gen, __ATOMIC_ACQUIRE, __HIP_MEMORY_SCOPE_AGENT) == g)
                __builtin_amdgcn_s_sleep(2);
    }
    __syncthreads();
}

// ---------------------------------------------------------------------------
// f32 -> bf16 conversion (flat, 4 elems/thread; n4 = count/4)
// ---------------------------------------------------------------------------
__global__ __launch_bounds__(256) void cvt_kernel(
    const float* __restrict__ src, ushort* __restrict__ dst, int n4)
{
    int i = blockIdx.x * 256 + threadIdx.x;
    if (i >= n4) return;
    float4 v = ((const float4*)src)[i];
    ushort4 o; o.x = f2b(v.x); o.y = f2b(v.y); o.z = f2b(v.z); o.w = f2b(v.w);
    ((ushort4*)dst)[i] = o;
}

// W_ih0 (3072 x 576) -> first 512 cols as bf16 (3072 x 512)
__global__ __launch_bounds__(256) void cvt_strided_kernel(
    const float* __restrict__ src, ushort* __restrict__ dst)
{
    int i = blockIdx.x * 256 + threadIdx.x;       // 393216 total
    int r = i >> 7, c4 = (i & 127) * 4;
    float4 v = *(const float4*)(src + (size_t)r * 576 + c4);
    ushort4 o; o.x = f2b(v.x); o.y = f2b(v.y); o.z = f2b(v.z); o.w = f2b(v.w);
    *(ushort4*)(dst + (size_t)r * 512 + c4) = o;
}

// ---------------------------------------------------------------------------
// Gb[d][v][c] = bf16(sum_k relu(tab[v][k]) * W_e0[c][d*64+k])  (d<128,v<64,c<1024)
// grid: (16 c-tiles, 128 d), 256 threads
// ---------------------------------------------------------------------------
__global__ __launch_bounds__(256) void build_g_kernel(
    const float* __restrict__ tab, const float* __restrict__ W0, ushort* __restrict__ Gb)
{
    __shared__ float Ts[64][68];
    __shared__ float Ws[64][68];
    const int d  = blockIdx.y;
    const int c0 = blockIdx.x * 64;
    const int tid = threadIdx.x;
    const int lr = tid >> 4, lc4 = (tid & 15) * 4;
#pragma unroll
    for (int i = 0; i < 4; ++i) {
        int r = lr + 16 * i;
        float4 tv = *(const float4*)(tab + r * 64 + lc4);
        tv.x = fmaxf(tv.x, 0.f); tv.y = fmaxf(tv.y, 0.f);
        tv.z = fmaxf(tv.z, 0.f); tv.w = fmaxf(tv.w, 0.f);
        *(float4*)&Ts[r][lc4] = tv;
        *(float4*)&Ws[r][lc4] = *(const float4*)(W0 + (size_t)(c0 + r) * 8192 + d * 64 + lc4);
    }
    __syncthreads();
    const int tx = tid & 15, ty = tid >> 4;
    float acc[4][4] = {};
#pragma unroll
    for (int k4 = 0; k4 < 16; ++k4) {
        float4 a[4], b[4];
#pragma unroll
        for (int i = 0; i < 4; ++i) a[i] = *(const float4*)&Ts[ty + 16 * i][k4 * 4];
#pragma unroll
        for (int j = 0; j < 4; ++j) b[j] = *(const float4*)&Ws[tx + 16 * j][k4 * 4];
#pragma unroll
        for (int i = 0; i < 4; ++i)
#pragma unroll
            for (int j = 0; j < 4; ++j) acc[i][j] += dot4(a[i], b[j]);
    }
#pragma unroll
    for (int i = 0; i < 4; ++i)
#pragma unroll
        for (int j = 0; j < 4; ++j)
            Gb[(size_t)(d * 64 + ty + 16 * i) * 1024 + c0 + tx + 16 * j] = f2b(acc[i][j]);
}

// ---------------------------------------------------------------------------
// OptG[v][c] = b_ih0[c] + sum_{k<64} opt_table[v][k] * W_ih0[c][512+k]  (c<3072)
// ---------------------------------------------------------------------------
__global__ __launch_bounds__(256) void optg_kernel(
    const float* __restrict__ ot, const float* __restrict__ Wih0,
    const float* __restrict__ bih0, float* __restrict__ OptG)
{
    __shared__ float Ts[64][68];
    __shared__ float Ws[64][68];
    const int c0 = blockIdx.x * 64;
    const int tid = threadIdx.x;
    const int lr = tid >> 4, lc4 = (tid & 15) * 4;
#pragma unroll
    for (int i = 0; i < 4; ++i) {
        int r = lr + 16 * i;
        *(float4*)&Ts[r][lc4] = *(const float4*)(ot + r * 64 + lc4);
        *(float4*)&Ws[r][lc4] = *(const float4*)(Wih0 + (size_t)(c0 + r) * 576 + 512 + lc4);
    }
    __syncthreads();
    const int tx = tid & 15, ty = tid >> 4;
    float acc[4][4] = {};
#pragma unroll
    for (int k4 = 0; k4 < 16; ++k4) {
        float4 a[4], b[4];
#pragma unroll
        for (int i = 0; i < 4; ++i) a[i] = *(const float4*)&Ts[ty + 16 * i][k4 * 4];
#pragma unroll
        for (int j = 0; j < 4; ++j) b[j] = *(const float4*)&Ws[tx + 16 * j][k4 * 4];
#pragma unroll
        for (int i = 0; i < 4; ++i)
#pragma unroll
            for (int j = 0; j < 4; ++j) acc[i][j] += dot4(a[i], b[j]);
    }
#pragma unroll
    for (int i = 0; i < 4; ++i)
#pragma unroll
        for (int j = 0; j < 4; ++j) {
            int c = c0 + tx + 16 * j;
            OptG[(size_t)(ty + 16 * i) * 3072 + c] = acc[i][j] + bih0[c];
        }
}

// ---------------------------------------------------------------------------
// E1b[m][c] = bf16(relu(b_e0[c] + sum_{d<128} Gb[d][obs[m][d]][c]))
// grid: (16 c-tiles, 32 m-tiles of 128), 256 threads
// ---------------------------------------------------------------------------
__global__ __launch_bounds__(256) void embsum_kernel(
    const int* __restrict__ obs, const ushort* __restrict__ Gb,
    const float* __restrict__ b0, ushort* __restrict__ E1b)
{
    __shared__ int   obs_s[128][32];
    __shared__ float Gs[64][68];
    const int c0 = blockIdx.x * 64;
    const int m0 = blockIdx.y * 128;
    const int tid = threadIdx.x;
    const int tx = tid & 15, my = tid >> 4;
    float acc[8][4] = {};
    for (int ch = 0; ch < 4; ++ch) {
#pragma unroll
        for (int q = 0; q < 4; ++q) {
            int idx = tid + 256 * q;           // 1024 int4 total
            int m = idx >> 3, d4 = (idx & 7) * 4;
            *(int4*)&obs_s[m][d4] = *(const int4*)(obs + (size_t)(m0 + m) * 128 + ch * 32 + d4);
        }
        for (int dd = 0; dd < 32; ++dd) {
#pragma unroll
            for (int q = 0; q < 2; ++q) {
                int idx = tid + 256 * q;       // 512 chunks of 8 bf16
                int v = idx >> 3, c8 = (idx & 7) * 8;
                uint4 gv = *(const uint4*)(Gb + (size_t)((ch * 32 + dd) * 64 + v) * 1024 + c0 + c8);
                float* gr = &Gs[v][c8];
                gr[0] = __uint_as_float(gv.x << 16);
                gr[1] = __uint_as_float(gv.x & 0xffff0000u);
                gr[2] = __uint_as_float(gv.y << 16);
                gr[3] = __uint_as_float(gv.y & 0xffff0000u);
                gr[4] = __uint_as_float(gv.z << 16);
                gr[5] = __uint_as_float(gv.z & 0xffff0000u);
                gr[6] = __uint_as_float(gv.w << 16);
                gr[7] = __uint_as_float(gv.w & 0xffff0000u);
            }
            __syncthreads();
#pragma unroll
            for (int i = 0; i < 8; ++i) {
                int o = obs_s[my + 16 * i][dd];
                float4 g = *(const float4*)&Gs[o][tx * 4];
                acc[i][0] += g.x; acc[i][1] += g.y; acc[i][2] += g.z; acc[i][3] += g.w;
            }
            __syncthreads();
        }
    }
#pragma unroll
    for (int i = 0; i < 8; ++i) {
        const int c = c0 + tx * 4;
        ushort4 o;
        o.x = f2b(fmaxf(acc[i][0] + b0[c + 0], 0.f));
        o.y = f2b(fmaxf(acc[i][1] + b0[c + 1], 0.f));
        o.z = f2b(fmaxf(acc[i][2] + b0[c + 2], 0.f));
        o.w = f2b(fmaxf(acc[i][3] + b0[c + 3], 0.f));
        *(ushort4*)(E1b + (size_t)(m0 + my + 16 * i) * 1024 + c) = o;
    }
}

// ---------------------------------------------------------------------------
// Shared bf16 MFMA GEMM body.  A [M][K] bf16, W [rows][K] bf16.
// Block: 4 waves, BM=64 (wave w owns rows m0+16w..+16), BN = CT*16, BK=64.
// LDS 16B chunks XOR-swizzled: slot = chunk ^ (row&7).
// MODE 0: Cb = bf16(relu(acc+bias))            MODE 1: Cf = acc+bias
// MODE 2: 3-gate gru0 -> Cb=bf16((1-z)*n)      MODE 3: 3-gate gru1 + relu
// MODE 4: CT=1, state: Cf=f32, Cb=bf16 dual store
// ---------------------------------------------------------------------------
template<int CT, int MODE>
__device__ __forceinline__ void gemm_body(
    const ushort* __restrict__ A, const ushort* __restrict__ W,
    const float* __restrict__ bias, const float* __restrict__ bhh,
    const float* __restrict__ OptG, const int* __restrict__ options, int jstep,
    int K, float* __restrict__ Cf, ushort* __restrict__ Cb, int NC,
    int bx, int m0, frag_ab* smem)
{
    constexpr int TOT = 512 + CT * 128;
    const int tid = threadIdx.x;
    frag_cd acc[CT] = {};
    const int lane = tid & 63, wv = tid >> 6;
    const int lr = lane & 15, lg = lane >> 4;

    for (int kt = 0; kt < K; kt += 64) {
        for (int q = tid; q < TOT; q += 256) {
            if (q < 512) {
                int r = q >> 3, cs = q & 7;
                smem[q] = *reinterpret_cast<const frag_ab*>(
                    A + (size_t)(m0 + r) * K + kt + ((cs ^ (r & 7)) << 3));
            } else {
                int qq = q - 512;
                int r = qq >> 3, cs = qq & 7;
                int wr;
                if (MODE == 2 || MODE == 3) wr = (r >> 4) * 1024 + bx * 16 + (r & 15);
                else                        wr = bx * (CT * 16) + r;
                smem[512 + qq] = *reinterpret_cast<const frag_ab*>(
                    W + (size_t)wr * K + kt + ((cs ^ (r & 7)) << 3));
            }
        }
        __syncthreads();
#pragma unroll
        for (int ks = 0; ks < 2; ++ks) {
            const int cc = ks * 4 + lg;
            const int ra = wv * 16 + lr;
            frag_ab av = smem[ra * 8 + (cc ^ (ra & 7))];
#pragma unroll
            for (int ct = 0; ct < CT; ++ct) {
                const int rb = ct * 16 + lr;
                frag_ab bv = smem[512 + rb * 8 + (cc ^ (rb & 7))];
                acc[ct] = __builtin_amdgcn_mfma_f32_16x16x32_bf16(av, bv, acc[ct], 0, 0, 0);
            }
        }
        __syncthreads();
    }

    // C/D layout: col = lane&15, row = (lane>>4)*4 + reg   [HW-verified]
    const int row0 = m0 + wv * 16 + lg * 4;
    if (MODE == 0 || MODE == 1) {
#pragma unroll
        for (int ct = 0; ct < CT; ++ct) {
            const int c = bx * (CT * 16) + ct * 16 + lr;
            const float bb = bias[c];
#pragma unroll
            for (int rg = 0; rg < 4; ++rg) {
                const int n = row0 + rg;
                float v = acc[ct][rg] + bb;
                if (MODE == 0) Cb[(size_t)n * NC + c] = f2b(fmaxf(v, 0.f));
                else           Cf[(size_t)n * NC + c] = v;
            }
        }
    } else if (MODE == 2 || MODE == 3) {
        const int c = bx * 16 + lr;
#pragma unroll
        for (int rg = 0; rg < 4; ++rg) {
            const int n = row0 + rg;
            float gr, gz, gn;
            if (MODE == 2) {
                const float* og = OptG + (size_t)options[n * 64 + jstep] * 3072;
                gr = acc[0][rg] + og[c];
                gz = acc[1][rg] + og[1024 + c];
                gn = acc[2][rg] + og[2048 + c];
            } else {
                gr = acc[0][rg] + bias[c];
                gz = acc[1][rg] + bias[1024 + c];
                gn = acc[2][rg] + bias[2048 + c];
            }
            float r  = sigmoidf_(gr + bhh[c]);
            float z  = sigmoidf_(gz + bhh[1024 + c]);
            float nn = tanhf(gn + r * bhh[2048 + c]);
            float h  = (1.f - z) * nn;
            if (MODE == 3) h = fmaxf(h, 0.f);
            Cb[(size_t)n * 1024 + c] = f2b(h);
        }
    } else {  // MODE 4
        const int c = bx * 16 + lr;
        const float bb = bias[c];
#pragma unroll
        for (int rg = 0; rg < 4; ++rg) {
            const int n = row0 + rg;
            float v = acc[0][rg] + bb;
            Cf[(size_t)n * 512 + c] = v;
            Cb[(size_t)n * 512 + c] = f2b(v);
        }
    }
}

// ---------------------------------------------------------------------------
// Critic for one n (f32): sharp/v/log_softmax/lp/ent + states/values writes.
// sm: >= 576 floats of shared scratch.
// ---------------------------------------------------------------------------
__device__ __forceinline__ void critic_body(
    int n, int jstep, const float* __restrict__ stateF,
    const float* __restrict__ Wsharp, const float* __restrict__ bsharp,
    const float* __restrict__ Wcrit, const float* __restrict__ bcrit,
    const int* __restrict__ options, float* __restrict__ lp,
    float* __restrict__ ent, float* __restrict__ outhx, float* sm)
{
    const int tid = threadIdx.x;
    float* rxs = sm;          // 512
    float* vv  = sm + 512;    // 64
#pragma unroll
    for (int q = 0; q < 2; ++q) {
        int k = tid + 256 * q;
        float s = stateF[(size_t)n * 512 + k];
        outhx[(size_t)n * ROW + 64 + (size_t)jstep * 512 + k] = s;  // states_seq (t=0 row)
        rxs[k] = fmaxf(s, 0.f);
    }
    __syncthreads();
    {
        const int o = tid >> 2, sg = tid & 3;
        const float* wr = Wcrit + o * 512 + sg * 128;
        const float* xr = rxs + sg * 128;
        float p = 0.f;
#pragma unroll
        for (int k4 = 0; k4 < 32; ++k4)
            p += dot4(*(const float4*)(xr + k4 * 4), *(const float4*)(wr + k4 * 4));
        p += __shfl_xor(p, 1);
        p += __shfl_xor(p, 2);
        if (sg == 0) vv[o] = p + bcrit[o];
    }
    __syncthreads();
    if (tid < 64) {
        const int l = tid;
        float sp = dot4(*(const float4*)(rxs + l * 8),     *(const float4*)(Wsharp + l * 8)) +
                   dot4(*(const float4*)(rxs + l * 8 + 4), *(const float4*)(Wsharp + l * 8 + 4));
#pragma unroll
        for (int m = 1; m < 64; m <<= 1) sp += __shfl_xor(sp, m);
        float sharp = softplusf_(sp + bsharp[0]);
        float v = vv[l];
        outhx[(size_t)n * ROW + 32899 + (size_t)jstep * 64 + l] = v;  // values_seq
        float x = sharp * v;
        float mx = x;
#pragma unroll
        for (int m = 1; m < 64; m <<= 1) mx = fmaxf(mx, __shfl_xor(mx, m));
        float e = expf(x - mx);
        float se = e;
#pragma unroll
        for (int m = 1; m < 64; m <<= 1) se += __shfl_xor(se, m);
        float logp = x - mx - logf(se);
        float entl = (e / se) * logp;
#pragma unroll
        for (int m = 1; m < 64; m <<= 1) entl += __shfl_xor(entl, m);
        const int opt = options[n * 64 + jstep];
        float lps = (l == opt) ? logp : 0.f;
#pragma unroll
        for (int m = 1; m < 64; m <<= 1) lps += __shfl_xor(lps, m);
        if (l == 0) {
            float lpo = (jstep == 0) ? 0.f : lp[n];
            float eno = (jstep == 0) ? 0.f : ent[n];
            lp[n]  = lpo + lps;
            ent[n] = eno - entl;
        }
    }
    __syncthreads();
}

// ---------------------------------------------------------------------------
// Standalone MFMA GEMM kernel (phase-1 MODEs 0/1)
// ---------------------------------------------------------------------------
template<int CT, int MODE>
__global__ __launch_bounds__(256) void mfma_gemm_k(
    const ushort* __restrict__ A, const ushort* __restrict__ W,
    const float* __restrict__ bias, float* __restrict__ Cf,
    ushort* __restrict__ Cb, int K, int NC)
{
    __shared__ frag_ab smem[512 + CT * 128];
    gemm_body<CT, MODE>(A, W, bias, nullptr, nullptr, nullptr, 0, K, Cf, Cb, NC,
                        blockIdx.x, blockIdx.y * 64, smem);
}

// ---------------------------------------------------------------------------
// Persistent scan kernel: 64 steps, 3 phases/step, tree grid-barrier between.
// 256 blocks x 256 threads. Phase A: gru0 GEMM (bx=bid&63, my=bid>>6) + critic
// (n=bid). Phase B: gru1. Phase C (bid<128): state GEMM.
// ---------------------------------------------------------------------------
__global__ __launch_bounds__(256) void scan_kernel(
    ushort* __restrict__ stateB, float* __restrict__ state,
    ushort* __restrict__ h0b, ushort* __restrict__ h1b,
    const ushort* __restrict__ Wih0b, const ushort* __restrict__ Wih1b,
    const ushort* __restrict__ Wemb2b,
    const float* __restrict__ b_ih1, const float* __restrict__ b_hh0,
    const float* __restrict__ b_hh1, const float* __restrict__ b_emb2,
    const float* __restrict__ OptG, const int* __restrict__ options,
    const float* __restrict__ Wsharp, const float* __restrict__ bsharp,
    const float* __restrict__ Wcrit, const float* __restrict__ bcrit,
    float* __restrict__ lp, float* __restrict__ ent,
    float* __restrict__ outhx, int* __restrict__ bar)
{
    __shared__ frag_ab smem[896];
    const int bid = blockIdx.x;
    for (int j = 0; j < 64; ++j) {
        // ---- phase A: gru0 GEMM + critic ----
        gemm_body<3, 2>(stateB, Wih0b, nullptr, b_hh0, OptG, options, j,
                        512, nullptr, h0b, 1024, bid & 63, (bid >> 6) * 64, smem);
        __syncthreads();
        critic_body(bid, j, state, Wsharp, bsharp, Wcrit, bcrit, options,
                    lp, ent, outhx, reinterpret_cast<float*>(smem));
        if (j == 63) return;            // uniform exit: h0/h1/state of step 63 unused
        gbar(bar);
        // ---- phase B: gru1 ----
        gemm_body<3, 3>(h0b, Wih1b, b_ih1, b_hh1, nullptr, nullptr, 0,
                        1024, nullptr, h1b, 1024, bid & 63, (bid >> 6) * 64, smem);
        gbar(bar);
        // ---- phase C: state = h1 @ Wemb2^T + b (f32 + bf16) ----
        if (bid < 128)
            gemm_body<1, 4>(h1b, Wemb2b, b_emb2, nullptr, nullptr, nullptr, 0,
                            1024, state, stateB, 512, bid & 31, (bid >> 5) * 64, smem);
        gbar(bar);
    }
}

// ---------------------------------------------------------------------------
// Output assembly.
// ---------------------------------------------------------------------------
__global__ __launch_bounds__(256) void out_kernel(
    const float* __restrict__ emb_all, const float* __restrict__ lp,
    const float* __restrict__ ent, const int* __restrict__ options,
    float* __restrict__ out)
{
    const int b = blockIdx.x;
    const int t = b >> 8, n = b & 255;
    const size_t base = (size_t)b * ROW;
    const size_t src0 = (size_t)n * ROW;
    const int tid = threadIdx.x;

    if (tid < 64) out[base + tid] = (float)tid;                 // indices
    if (t > 0)
        for (int idx = tid; idx < 32768; idx += 256)            // states tile
            out[base + 64 + idx] = out[src0 + 64 + idx];

    float s = 0.f;                                              // model_loss
#pragma unroll
    for (int q = 0; q < 2; ++q) {
        int e = tid + 256 * q;
        float d = out[src0 + 64 + (size_t)t * 512 + e] - emb_all[(size_t)(t * 256 + n) * 512 + e];
        s += d * d;
    }
#pragma unroll
    for (int m = 1; m < 64; m <<= 1) s += __shfl_xor(s, m);
    __shared__ float red[4];
    if ((tid & 63) == 0) red[tid >> 6] = s;
    __syncthreads();

    if (tid < 64) out[base + 32835 + tid] = (float)options[n * 64 + tid];   // options
    if (t > 0)
        for (int idx = tid; idx < 4096; idx += 256)             // values tile
            out[base + 32899 + idx] = out[src0 + 32899 + idx];

    if (tid == 0) {
        float ml = (red[0] + red[1] + red[2] + red[3]) * (1.f / 512.f);
        out[base + 32832] = ml;
        out[base + 32833] = lp[n];
        out[base + 32834] = ent[n];
        int ot = options[n * 64 + t];
        out[base + 36995] = (float)ot;                                      // a
        out[base + 36996] = out[src0 + 32899 + (size_t)t * 64 + ot];        // v_sel
    }
}

// ---------------------------------------------------------------------------
extern "C" void kernel_launch(void* const* d_in, const int* in_sizes, int n_in,
                              void* d_out, int out_size, void* d_ws, size_t ws_size,
                              hipStream_t stream)
{
    (void)in_sizes; (void)n_in; (void)out_size; (void)ws_size;

    const int*   obs      = (const int*)  d_in[0];
    const int*   options  = (const int*)  d_in[1];
    const float* tab      = (const float*)d_in[2];
    const float* W_e0     = (const float*)d_in[3];
    const float* b_e0     = (const float*)d_in[4];
    const float* W_e1     = (const float*)d_in[5];
    const float* b_e1     = (const float*)d_in[6];
    const float* W_emb2   = (const float*)d_in[7];
    const float* b_emb2   = (const float*)d_in[8];
    const float* W_sharp  = (const float*)d_in[9];
    const float* b_sharp  = (const float*)d_in[10];
    const float* W_crit   = (const float*)d_in[11];
    const float* b_crit   = (const float*)d_in[12];
    const float* opt_tab  = (const float*)d_in[13];
    const float* W_ih0    = (const float*)d_in[14];
    // d_in[15] = W_hh0  (unused: hidden state is always zero -> gh = b_hh)
    const float* b_ih0    = (const float*)d_in[16];
    const float* b_hh0    = (const float*)d_in[17];
    const float* W_ih1    = (const float*)d_in[18];
    // d_in[19] = W_hh1  (unused)
    const float* b_ih1    = (const float*)d_in[20];
    const float* b_hh1    = (const float*)d_in[21];

    float* out = (float*)d_out;
    float* ws  = (float*)d_ws;

    // ---- workspace layout (total ~55 MB) ----
    float*  OptG    = ws;                         //   196,608 f
    float*  emb_all = OptG + 196608;              // 2,097,152 f
    float*  state   = emb_all + 2097152;          //   131,072 f
    float*  lp      = state + 131072;             //       256 f
    float*  ent     = lp + 256;                   //       256 f
    int*    bar     = (int*)(ent + 256);          //       512 i
    ushort* Gb      = (ushort*)(bar + 512);       // 8,388,608 u
    ushort* E1b     = Gb + 8388608;               // 4,194,304 u
    ushort* E2b     = E1b + 4194304;              // 4,194,304 u
    ushort* We1b    = E2b + 4194304;              // 1,048,576 u
    ushort* Wemb2b  = We1b + 1048576;             //   524,288 u
    ushort* Wih0b   = Wemb2b + 524288;            // 1,572,864 u
    ushort* Wih1b   = Wih0b + 1572864;            // 3,145,728 u
    ushort* stateB  = Wih1b + 3145728;            //   131,072 u
    ushort* h0b     = stateB + 131072;            //   262,144 u
    ushort* h1b     = h0b + 262144;               //   262,144 u

    hipMemsetAsync(bar, 0, 2048, stream);

    // ---- phase 0: weight conversions ----
    cvt_kernel<<<1024, 256, 0, stream>>>(W_e1,   We1b,   262144);
    cvt_kernel<<< 512, 256, 0, stream>>>(W_emb2, Wemb2b, 131072);
    cvt_kernel<<<3072, 256, 0, stream>>>(W_ih1,  Wih1b,  786432);
    cvt_strided_kernel<<<1536, 256, 0, stream>>>(W_ih0, Wih0b);

    // ---- phase 1: embedding pipeline ----
    build_g_kernel<<<dim3(16, 128), 256, 0, stream>>>(tab, W_e0, Gb);
    optg_kernel<<<48, 256, 0, stream>>>(opt_tab, W_ih0, b_ih0, OptG);
    embsum_kernel<<<dim3(16, 32), 256, 0, stream>>>(obs, Gb, b_e0, E1b);
    mfma_gemm_k<4, 0><<<dim3(16, 64), 256, 0, stream>>>(
        E1b, We1b, b_e1, nullptr, E2b, 1024, 1024);
    mfma_gemm_k<4, 1><<<dim3(8, 64), 256, 0, stream>>>(
        E2b, Wemb2b, b_emb2, emb_all, nullptr, 1024, 512);

    // state = emb_all[t=0]; stateB = bf16(state)
    hipMemcpyAsync(state, emb_all, (size_t)131072 * sizeof(float),
                   hipMemcpyDeviceToDevice, stream);
    cvt_kernel<<<128, 256, 0, stream>>>(emb_all, stateB, 32768);

    // ---- phase 2: persistent planning scan (single launch) ----
    scan_kernel<<<NBLK, 256, 0, stream>>>(
        stateB, state, h0b, h1b, Wih0b, Wih1b, Wemb2b,
        b_ih1, b_hh0, b_hh1, b_emb2, OptG, options,
        W_sharp, b_sharp, W_crit, b_crit, lp, ent, out, bar);

    // ---- phase 3: output assembly ----
    out_kernel<<<4096, 256, 0, stream>>>(emb_all, lp, ent, options, out);

    // hx[-1:] = copy of the t=15 slab
    hipMemcpyAsync(out + (size_t)16 * 256 * ROW,
                   out + (size_t)15 * 256 * ROW,
                   (size_t)256 * ROW * sizeof(float),
                   hipMemcpyDeviceToDevice, stream);
}